// Round 10
// baseline (658.864 us; speedup 1.0000x reference)
//
#include <hip/hip_runtime.h>
#include <hip/hip_cooperative_groups.h>

namespace cg = cooperative_groups;

#define N_USER 50000
#define N_ITEM 30000
#define DIM    64
#define NTOT   80000
#define NNZ_UI 1000000
#define NNZ_R  800000
#define NNZ_II 300000
#define IMG_F  512
#define TXT_F  384

#define NROWS_ALL 190000            // NTOT + N_USER + N_ITEM + N_ITEM
#define NNZ_ALL   2400000           // NNZ_UI + NNZ_R + 2*NNZ_II
#define BASE_R    NTOT              // 80000
#define BASE_II   (NTOT + N_USER)   // 130000
#define BASE_IT   (NTOT + N_USER + N_ITEM) // 160000

// row-bucketed CSR build: 512 rows per bucket
#define RB_BITS   9
#define RB_ROWS   512
#define NBUCK     ((NROWS_ALL + RB_ROWS - 1) / RB_ROWS)   // 372
#define NBLK_A2   400
#define EDG_A2    6000              // 400 * 6000 == NNZ_ALL exactly

#define NBLK_PG   625               // N_ITEM / 48
#define NBLK_UIP  5000              // NTOT*16/256
#define NBLK_I16  1875              // N_ITEM*16/256
#define NBLK_U16  3125              // N_USER*16/256
#define NBLK_CP   1875              // N_ITEM*DIM/1024 float4-copy blocks

#define NBLK_M1   (2 * NBLK_PG + NBLK_UIP)          // 6250, projgate FIRST
#define NBLK_M2   (NBLK_UIP + 2 * NBLK_I16)         // 8750, pull_mean first
#define NBLK_RC   (NBLK_U16 + 2 * NBLK_CP)          // 6875

// ---------------- edge decode helpers (fused 4-list view) ----------------
__device__ __forceinline__ int edge_row(int i,
        const int* __restrict__ r0, const int* __restrict__ r1,
        const int* __restrict__ r2, const int* __restrict__ r3){
    if (i < NNZ_UI)                       return r0[i];
    if (i < NNZ_UI + NNZ_R)               return BASE_R  + r1[i - NNZ_UI];
    if (i < NNZ_UI + NNZ_R + NNZ_II)      return BASE_II + r2[i - NNZ_UI - NNZ_R];
    return BASE_IT + r3[i - NNZ_UI - NNZ_R - NNZ_II];
}

__device__ __forceinline__ void edge_all(int i,
        const int* __restrict__ r0, const int* __restrict__ c0, const float* __restrict__ v0,
        const int* __restrict__ r1, const int* __restrict__ c1, const float* __restrict__ v1,
        const int* __restrict__ r2, const int* __restrict__ c2, const float* __restrict__ v2,
        const int* __restrict__ r3, const int* __restrict__ c3, const float* __restrict__ v3,
        int& gr, int& col, float& val){
    if (i < NNZ_UI){
        gr = r0[i]; col = c0[i]; val = v0[i];
    } else if (i < NNZ_UI + NNZ_R){
        int j = i - NNZ_UI;               gr = BASE_R  + r1[j]; col = c1[j]; val = v1[j];
    } else if (i < NNZ_UI + NNZ_R + NNZ_II){
        int j = i - NNZ_UI - NNZ_R;       gr = BASE_II + r2[j]; col = c2[j]; val = v2[j];
    } else {
        int j = i - NNZ_UI - NNZ_R - NNZ_II; gr = BASE_IT + r3[j]; col = c3[j]; val = v3[j];
    }
}

// ---------------- build 1-3 fused (cooperative): hist -> scan -> bin ----------
// 400 co-resident blocks. Per-block local bucket hist (LDS, survives grid
// syncs) is used BOTH for the global histogram contribution and for the
// per-block chunk reservation — the separate k_bhist edge pass is gone.
__global__ __launch_bounds__(256) void k_build123(
        const int* __restrict__ r0, const int* __restrict__ c0, const float* __restrict__ v0,
        const int* __restrict__ r1, const int* __restrict__ c1, const float* __restrict__ v1,
        const int* __restrict__ r2, const int* __restrict__ c2, const float* __restrict__ v2,
        const int* __restrict__ r3, const int* __restrict__ c3, const float* __restrict__ v3,
        int* __restrict__ bcnt, int* __restrict__ bbase, int* __restrict__ off,
        int* __restrict__ bcur, int2* __restrict__ binned){
    __shared__ int lofs[NBUCK];
    __shared__ int lcur[NBUCK];
    const int t = threadIdx.x;
    for (int i = t; i < NBUCK; i += 256){ lofs[i] = 0; lcur[i] = 0; }
    __syncthreads();
    const int s0 = blockIdx.x * EDG_A2, s1 = s0 + EDG_A2;
    // pass 1: local bucket histogram
    for (int i = s0 + t; i < s1; i += 256){
        int gr = edge_row(i, r0, r1, r2, r3);
        atomicAdd(&lofs[gr >> RB_BITS], 1);
    }
    __syncthreads();
    // contribute to global bucket counts
    for (int i = t; i < NBUCK; i += 256){
        int c = lofs[i];
        if (c) atomicAdd(&bcnt[i], c);
    }
    cg::this_grid().sync();
    // block 0, wave 0: exclusive scan of 372 bucket counts (8/lane + shfl)
    if (blockIdx.x == 0 && t < 64){
        int v[8], s = 0;
#pragma unroll
        for (int k = 0; k < 8; ++k){
            int idx = t * 8 + k;
            v[k] = (idx < NBUCK) ? bcnt[idx] : 0;
            s += v[k];
        }
        int incl = s;
#pragma unroll
        for (int d = 1; d < 64; d <<= 1){
            int u = __shfl_up(incl, d, 64);
            if (t >= d) incl += u;
        }
        int run = incl - s;
#pragma unroll
        for (int k = 0; k < 8; ++k){
            int idx = t * 8 + k;
            if (idx < NBUCK) bbase[idx] = run;
            run += v[k];
        }
        if (t == 63){
            bbase[NBUCK] = run;       // grand total (== NNZ_ALL)
            off[NROWS_ALL] = run;
        }
    }
    cg::this_grid().sync();
    // reserve per-bucket chunks (one global atomic per (block,bucket))
    for (int i = t; i < NBUCK; i += 256){
        int c = lofs[i];
        lofs[i] = c ? (bbase[i] + atomicAdd(&bcur[i], c)) : 0;
    }
    __syncthreads();
    // pass 2: write packed records into this block's chunks
    for (int i = s0 + t; i < s1; i += 256){
        int gr, col; float val;
        edge_all(i, r0, c0, v0, r1, c1, v1, r2, c2, v2, r3, c3, v3, gr, col, val);
        int b = gr >> RB_BITS;
        int slot = atomicAdd(&lcur[b], 1);
        binned[lofs[b] + slot] = make_int2((col << RB_BITS) | (gr & (RB_ROWS - 1)),
                                           __float_as_int(val));
    }
}

// ---------------- build 4: per-bucket hist+scan+scatter (one block = one bucket)
__global__ __launch_bounds__(256) void k_scatter(const int* __restrict__ bbase,
        const int2* __restrict__ binned, int* __restrict__ off,
        int2* __restrict__ csr){
    __shared__ int h[RB_ROWS];
    const int t = threadIdx.x;
    const int b = blockIdx.x;
    const int base = bbase[b];
    const int nb = bbase[b + 1] - base;
    h[t] = 0; h[t + 256] = 0;
    __syncthreads();
    for (int i = t; i < nb; i += 256)
        atomicAdd(&h[binned[base + i].x & (RB_ROWS - 1)], 1);
    __syncthreads();
    if (t < 64){
        int v[8], s = 0;
#pragma unroll
        for (int k = 0; k < 8; ++k){ v[k] = h[t * 8 + k]; s += v[k]; }
        int incl = s;
#pragma unroll
        for (int d = 1; d < 64; d <<= 1){
            int u = __shfl_up(incl, d, 64);
            if (t >= d) incl += u;
        }
        int run = incl - s;
#pragma unroll
        for (int k = 0; k < 8; ++k){ int tmp = v[k]; h[t * 8 + k] = run; run += tmp; }
    }
    __syncthreads();
    const int row0 = b << RB_BITS;
    for (int i = t; i < RB_ROWS; i += 256){
        int r = row0 + i;
        if (r < NROWS_ALL) off[r] = base + h[i];
    }
    __syncthreads();
    for (int i = t; i < nb; i += 256){
        int2 rec = binned[base + i];
        int lr = rec.x & (RB_ROWS - 1);
        int slot = atomicAdd(&h[lr], 1);
        csr[base + slot] = make_int2(rec.x >> RB_BITS, rec.y);
    }
}

// ---------------- virtual cat = [item_emb; user_emb] row pointer ----------------
__device__ __forceinline__ const float* cat_row(int c,
        const float* __restrict__ item, const float* __restrict__ user){
    return (c < N_ITEM) ? (item + ((long)c << 6)) : (user + ((long)(c - N_ITEM) << 6));
}

// fma helper
__device__ __forceinline__ void fma4(float4& a, float v, const float4& x){
    a.x = fmaf(v, x.x, a.x);
    a.y = fmaf(v, x.y, a.y);
    a.z = fmaf(v, x.z, a.z);
    a.w = fmaf(v, x.w, a.w);
}

// ---------------- pull-SpMM body (4-deep: 4 gathers in flight) ----------------
__device__ __forceinline__ void pull_body(const int* __restrict__ off,
        const int2* __restrict__ csr, const float* __restrict__ x,
        float* __restrict__ y, int r, int l){
    int s = off[r], e = off[r + 1];
    float4 a0 = {0.f,0.f,0.f,0.f}, a1 = {0.f,0.f,0.f,0.f};
    float4 a2 = {0.f,0.f,0.f,0.f}, a3 = {0.f,0.f,0.f,0.f};
    int j = s;
    for (; j + 4 <= e; j += 4){
        int2 e0 = csr[j], e1 = csr[j+1], e2 = csr[j+2], e3 = csr[j+3];
        const float4 x0 = *reinterpret_cast<const float4*>(x + ((long)e0.x << 6) + l);
        const float4 x1 = *reinterpret_cast<const float4*>(x + ((long)e1.x << 6) + l);
        const float4 x2 = *reinterpret_cast<const float4*>(x + ((long)e2.x << 6) + l);
        const float4 x3 = *reinterpret_cast<const float4*>(x + ((long)e3.x << 6) + l);
        fma4(a0, __int_as_float(e0.y), x0);
        fma4(a1, __int_as_float(e1.y), x1);
        fma4(a2, __int_as_float(e2.y), x2);
        fma4(a3, __int_as_float(e3.y), x3);
    }
    for (; j < e; ++j){
        int2 e0 = csr[j];
        const float4 x0 = *reinterpret_cast<const float4*>(x + ((long)e0.x << 6) + l);
        fma4(a0, __int_as_float(e0.y), x0);
    }
    a0.x = (a0.x + a1.x) + (a2.x + a3.x);
    a0.y = (a0.y + a1.y) + (a2.y + a3.y);
    a0.z = (a0.z + a1.z) + (a2.z + a3.z);
    a0.w = (a0.w + a1.w) + (a2.w + a3.w);
    *reinterpret_cast<float4*>(y + ((long)r << 6) + l) = a0;
}

// pull body over the virtual cat (UI hop 1; no cat0 materialization)
__device__ __forceinline__ void pull_cat_body(const int* __restrict__ off,
        const int2* __restrict__ csr, const float* __restrict__ item,
        const float* __restrict__ user, float* __restrict__ y, int r, int l){
    int s = off[r], e = off[r + 1];
    float4 a0 = {0.f,0.f,0.f,0.f}, a1 = {0.f,0.f,0.f,0.f};
    float4 a2 = {0.f,0.f,0.f,0.f}, a3 = {0.f,0.f,0.f,0.f};
    int j = s;
    for (; j + 4 <= e; j += 4){
        int2 e0 = csr[j], e1 = csr[j+1], e2 = csr[j+2], e3 = csr[j+3];
        const float4 x0 = *reinterpret_cast<const float4*>(cat_row(e0.x, item, user) + l);
        const float4 x1 = *reinterpret_cast<const float4*>(cat_row(e1.x, item, user) + l);
        const float4 x2 = *reinterpret_cast<const float4*>(cat_row(e2.x, item, user) + l);
        const float4 x3 = *reinterpret_cast<const float4*>(cat_row(e3.x, item, user) + l);
        fma4(a0, __int_as_float(e0.y), x0);
        fma4(a1, __int_as_float(e1.y), x1);
        fma4(a2, __int_as_float(e2.y), x2);
        fma4(a3, __int_as_float(e3.y), x3);
    }
    for (; j < e; ++j){
        int2 e0 = csr[j];
        const float4 x0 = *reinterpret_cast<const float4*>(cat_row(e0.x, item, user) + l);
        fma4(a0, __int_as_float(e0.y), x0);
    }
    a0.x = (a0.x + a1.x) + (a2.x + a3.x);
    a0.y = (a0.y + a1.y) + (a2.y + a3.y);
    a0.z = (a0.z + a1.z) + (a2.z + a3.z);
    a0.w = (a0.w + a1.w) + (a2.w + a3.w);
    *reinterpret_cast<float4*>(y + ((long)r << 6) + l) = a0;
}

// UI hop-2 + content mean body: o0[r] = (cat_row(r) + x[r] + pull(x)[r]) / 3
__device__ __forceinline__ void pull_mean_body(const int* __restrict__ off,
        const int2* __restrict__ csr, const float* __restrict__ x,
        const float* __restrict__ item, const float* __restrict__ user,
        float* __restrict__ o0, int r, int l){
    int s = off[r], e = off[r + 1];
    float4 a0 = {0.f,0.f,0.f,0.f}, a1 = {0.f,0.f,0.f,0.f};
    float4 a2 = {0.f,0.f,0.f,0.f}, a3 = {0.f,0.f,0.f,0.f};
    int j = s;
    for (; j + 4 <= e; j += 4){
        int2 e0 = csr[j], e1 = csr[j+1], e2 = csr[j+2], e3 = csr[j+3];
        const float4 x0 = *reinterpret_cast<const float4*>(x + ((long)e0.x << 6) + l);
        const float4 x1 = *reinterpret_cast<const float4*>(x + ((long)e1.x << 6) + l);
        const float4 x2 = *reinterpret_cast<const float4*>(x + ((long)e2.x << 6) + l);
        const float4 x3 = *reinterpret_cast<const float4*>(x + ((long)e3.x << 6) + l);
        fma4(a0, __int_as_float(e0.y), x0);
        fma4(a1, __int_as_float(e1.y), x1);
        fma4(a2, __int_as_float(e2.y), x2);
        fma4(a3, __int_as_float(e3.y), x3);
    }
    for (; j < e; ++j){
        int2 e0 = csr[j];
        const float4 x0 = *reinterpret_cast<const float4*>(x + ((long)e0.x << 6) + l);
        fma4(a0, __int_as_float(e0.y), x0);
    }
    a0.x = (a0.x + a1.x) + (a2.x + a3.x);
    a0.y = (a0.y + a1.y) + (a2.y + a3.y);
    a0.z = (a0.z + a1.z) + (a2.z + a3.z);
    a0.w = (a0.w + a1.w) + (a2.w + a3.w);
    const float4 av = *reinterpret_cast<const float4*>(cat_row(r, item, user) + l);
    const float4 xv = *reinterpret_cast<const float4*>(x + ((long)r << 6) + l);
    float4 o;
    o.x = (av.x + xv.x + a0.x) * (1.0f / 3.0f);
    o.y = (av.y + xv.y + a0.y) * (1.0f / 3.0f);
    o.z = (av.z + xv.z + a0.z) * (1.0f / 3.0f);
    o.w = (av.w + xv.w + a0.w) * (1.0f / 3.0f);
    *reinterpret_cast<float4*>(o0 + ((long)r << 6) + l) = o;
}

// two independent pulls in one launch (same nrows for both halves)
__global__ void k_pull2(const int* __restrict__ offA, const int2* __restrict__ csr,
                        const float* __restrict__ xA, float* __restrict__ yA,
                        const int* __restrict__ offB, const float* __restrict__ xB,
                        float* __restrict__ yB, int nrows, int nblk_half){
    int b = blockIdx.x;
    const int* off; const float* x; float* y;
    if (b < nblk_half){ off = offA; x = xA; y = yA; }
    else              { b -= nblk_half; off = offB; x = xB; y = yB; }
    int t = b * 256 + threadIdx.x;
    int r = t >> 4;
    if (r >= nrows) return;
    pull_body(off, csr, x, y, r, (t & 15) << 2);
}

// ---------------- MEGA1: projgate FIRST (round-8 body), then UI-hop1 pulls ----
// blocks [0,1250): projgate (img then txt); blocks [1250,6250): UI hop-1 pull.
// K-chunk 64, single-phase gate — the measured-best projgate variant.
__global__ __launch_bounds__(256) void k_mega1(
        const int* __restrict__ offUI, const int2* __restrict__ csr,
        const float* __restrict__ user,
        float* __restrict__ hop1out,
        const float* __restrict__ Xi, const float* __restrict__ Wi,
        const float* __restrict__ bi, const float* __restrict__ gi,
        const float* __restrict__ bei, const float* __restrict__ Wgi,
        const float* __restrict__ bgi,
        const float* __restrict__ Xt, const float* __restrict__ Wt,
        const float* __restrict__ bt, const float* __restrict__ gt,
        const float* __restrict__ bet, const float* __restrict__ Wgt,
        const float* __restrict__ bgt,
        const float* __restrict__ item,
        float* __restrict__ Pi, float* __restrict__ Pt){
    __shared__ float xs[48][68];    // +4 pad: conflict-free, f4-aligned
    __shared__ float ws[64][64];

    if (blockIdx.x >= 2 * NBLK_PG){
        // ---- UI hop-1 pull path (5000 blocks; exact: r < NTOT) ----
        int pb = blockIdx.x - 2 * NBLK_PG;
        int t = pb * 256 + threadIdx.x;
        int r = t >> 4;
        pull_cat_body(offUI, csr, item, user, hop1out, r, (t & 15) << 2);
        return;
    }

    // ---- projgate path (1250 blocks) ----
    const int t  = threadIdx.x;
    const int tr = t >> 4;          // 0..15
    const int tc = t & 15;          // 0..15
    const int pgb = blockIdx.x;
    const bool isTxt = pgb >= NBLK_PG;
    const int  blk   = isTxt ? (pgb - NBLK_PG) : pgb;
    const int  K     = isTxt ? TXT_F : IMG_F;
    const float* X   = isTxt ? Xt  : Xi;
    const float* W   = isTxt ? Wt  : Wi;
    const float* bb  = isTxt ? bt  : bi;
    const float* gg  = isTxt ? gt  : gi;
    const float* be  = isTxt ? bet : bei;
    const float* Wg  = isTxt ? Wgt : Wgi;
    const float* bg  = isTxt ? bgt : bgi;
    float* outP      = isTxt ? Pt  : Pi;
    const int row0   = blk * 48;

    float acc[3][4];
#pragma unroll
    for (int i = 0; i < 3; ++i)
#pragma unroll
        for (int j = 0; j < 4; ++j) acc[i][j] = 0.f;

    for (int ks = 0; ks < K; ks += 64){
        __syncthreads();
        // stage X tile [48][64]
#pragma unroll
        for (int i = 0; i < 3; ++i){
            int r = tr + 16 * i;
            *reinterpret_cast<float4*>(&xs[r][tc * 4]) =
                *reinterpret_cast<const float4*>(X + (long)(row0 + r) * K + ks + tc * 4);
        }
        // stage W tile [64][64] (contiguous 16 KB)
        {
            const float4* wsrc = reinterpret_cast<const float4*>(W + (long)ks * 64);
            float4* wdst = reinterpret_cast<float4*>(&ws[0][0]);
#pragma unroll
            for (int i = 0; i < 4; ++i) wdst[t + 256 * i] = wsrc[t + 256 * i];
        }
        __syncthreads();
#pragma unroll 8
        for (int kk = 0; kk < 64; kk += 2){
            float2 a[3];
#pragma unroll
            for (int i = 0; i < 3; ++i)
                a[i] = *reinterpret_cast<const float2*>(&xs[tr + 16 * i][kk]);
            float4 b0 = *reinterpret_cast<const float4*>(&ws[kk][tc * 4]);
            float4 b1 = *reinterpret_cast<const float4*>(&ws[kk + 1][tc * 4]);
#pragma unroll
            for (int i = 0; i < 3; ++i){
                acc[i][0] = fmaf(a[i].x, b0.x, acc[i][0]);
                acc[i][1] = fmaf(a[i].x, b0.y, acc[i][1]);
                acc[i][2] = fmaf(a[i].x, b0.z, acc[i][2]);
                acc[i][3] = fmaf(a[i].x, b0.w, acc[i][3]);
                acc[i][0] = fmaf(a[i].y, b1.x, acc[i][0]);
                acc[i][1] = fmaf(a[i].y, b1.y, acc[i][1]);
                acc[i][2] = fmaf(a[i].y, b1.z, acc[i][2]);
                acc[i][3] = fmaf(a[i].y, b1.w, acc[i][3]);
            }
        }
    }

    // ---- epilogue 1: feat = leaky(BN(acc + b)) -> xs; stage Wg -> ws ----
    const float4 b4  = reinterpret_cast<const float4*>(bb)[tc];
    const float4 g4  = reinterpret_cast<const float4*>(gg)[tc];
    const float4 be4 = reinterpret_cast<const float4*>(be)[tc];
    __syncthreads();    // all reads of xs/ws done
#pragma unroll
    for (int i = 0; i < 3; ++i){
        int r = tr + 16 * i;
        float4 h;
        h.x = (acc[i][0] + b4.x) * (g4.x * 0.99999500003749943f) + be4.x;
        h.y = (acc[i][1] + b4.y) * (g4.y * 0.99999500003749943f) + be4.y;
        h.z = (acc[i][2] + b4.z) * (g4.z * 0.99999500003749943f) + be4.z;
        h.w = (acc[i][3] + b4.w) * (g4.w * 0.99999500003749943f) + be4.w;
        h.x = (h.x >= 0.f) ? h.x : 0.01f * h.x;
        h.y = (h.y >= 0.f) ? h.y : 0.01f * h.y;
        h.z = (h.z >= 0.f) ? h.z : 0.01f * h.z;
        h.w = (h.w >= 0.f) ? h.w : 0.01f * h.w;
        *reinterpret_cast<float4*>(&xs[r][tc * 4]) = h;
    }
    {
        const float4* wsrc = reinterpret_cast<const float4*>(Wg);
        float4* wdst = reinterpret_cast<float4*>(&ws[0][0]);
#pragma unroll
        for (int i = 0; i < 4; ++i) wdst[t + 256 * i] = wsrc[t + 256 * i];
    }
    __syncthreads();

    // ---- gate GEMM: feat @ Wg (K = 64) ----
    float ac2[3][4];
#pragma unroll
    for (int i = 0; i < 3; ++i)
#pragma unroll
        for (int j = 0; j < 4; ++j) ac2[i][j] = 0.f;
#pragma unroll 8
    for (int kk = 0; kk < 64; kk += 2){
        float2 a[3];
#pragma unroll
        for (int i = 0; i < 3; ++i)
            a[i] = *reinterpret_cast<const float2*>(&xs[tr + 16 * i][kk]);
        float4 b0 = *reinterpret_cast<const float4*>(&ws[kk][tc * 4]);
        float4 b1 = *reinterpret_cast<const float4*>(&ws[kk + 1][tc * 4]);
#pragma unroll
        for (int i = 0; i < 3; ++i){
            ac2[i][0] = fmaf(a[i].x, b0.x, ac2[i][0]);
            ac2[i][1] = fmaf(a[i].x, b0.y, ac2[i][1]);
            ac2[i][2] = fmaf(a[i].x, b0.z, ac2[i][2]);
            ac2[i][3] = fmaf(a[i].x, b0.w, ac2[i][3]);
            ac2[i][0] = fmaf(a[i].y, b1.x, ac2[i][0]);
            ac2[i][1] = fmaf(a[i].y, b1.y, ac2[i][1]);
            ac2[i][2] = fmaf(a[i].y, b1.z, ac2[i][2]);
            ac2[i][3] = fmaf(a[i].y, b1.w, ac2[i][3]);
        }
    }

    // ---- epilogue 2: P = item * sigmoid(ac2 + bg) ----
    const float4 bg4 = reinterpret_cast<const float4*>(bg)[tc];
#pragma unroll
    for (int i = 0; i < 3; ++i){
        int r = tr + 16 * i;
        const float4 iv = *reinterpret_cast<const float4*>(
                item + (long)(row0 + r) * 64 + tc * 4);
        float4 o;
        o.x = iv.x / (1.f + __expf(-(ac2[i][0] + bg4.x)));
        o.y = iv.y / (1.f + __expf(-(ac2[i][1] + bg4.y)));
        o.z = iv.z / (1.f + __expf(-(ac2[i][2] + bg4.z)));
        o.w = iv.w / (1.f + __expf(-(ac2[i][3] + bg4.w)));
        *reinterpret_cast<float4*>(outP + (long)(row0 + r) * 64 + tc * 4) = o;
    }
}

// ---------------- MEGA2: UI hop-2 + mean, then modal hop-1 (CONTIGUOUS) -------
__global__ void k_mega2c(const int* __restrict__ offUI, const int2* __restrict__ csr,
        const float* __restrict__ hop1,         // o2 (read-only here)
        const float* __restrict__ item, const float* __restrict__ user,
        float* __restrict__ o0,
        const int* __restrict__ offI2, const float* __restrict__ P_img,
        float* __restrict__ Q_img,
        const int* __restrict__ offT2, const float* __restrict__ P_txt,
        float* __restrict__ Q_txt){
    const int tid = threadIdx.x;
    if (blockIdx.x < NBLK_UIP){
        int t = blockIdx.x * 256 + tid;
        int r = t >> 4;                         // exact: r < NTOT
        pull_mean_body(offUI, csr, hop1, item, user, o0, r, (t & 15) << 2);
    } else {
        int m = blockIdx.x - NBLK_UIP;          // 0..3750
        const int* off; const float* x; float* y;
        if (m < NBLK_I16){ off = offI2; x = P_img; y = Q_img; }
        else             { m -= NBLK_I16; off = offT2; x = P_txt; y = Q_txt; }
        int t = m * 256 + tid;
        int r = t >> 4;                         // exact: r < N_ITEM
        pull_body(off, csr, x, y, r, (t & 15) << 2);
    }
}

// ---------------- pullR + item-block copies in one launch ----------------
__global__ void k_pullRC(const int* __restrict__ off, const int2* __restrict__ csr,
                         const float* __restrict__ xA, float* __restrict__ yA,
                         const float* __restrict__ xB, float* __restrict__ yB,
                         float* __restrict__ dA, float* __restrict__ dB){
    int bid = blockIdx.x;
    const int tid = threadIdx.x;
    if (bid >= NBLK_U16){
        int c = bid - NBLK_U16;
        const float4* src; float4* dst;
        if (c < NBLK_CP){ src = reinterpret_cast<const float4*>(xA);
                          dst = reinterpret_cast<float4*>(dA); }
        else { c -= NBLK_CP; src = reinterpret_cast<const float4*>(xB);
               dst = reinterpret_cast<float4*>(dB); }
        int i = c * 256 + tid;                  // 480000 float4 per block set
        dst[i] = src[i];
        return;
    }
    int t = bid * 256 + tid;
    int r = t >> 4;                             // exact: r < N_USER
    int l = (t & 15) << 2;
    int s = off[r], e = off[r + 1];
    float4 pA0 = {0.f,0.f,0.f,0.f}, pA1 = {0.f,0.f,0.f,0.f};
    float4 pB0 = {0.f,0.f,0.f,0.f}, pB1 = {0.f,0.f,0.f,0.f};
    int j = s;
    for (; j + 2 <= e; j += 2){
        int2 e0 = csr[j];
        int2 e1 = csr[j + 1];
        float v0 = __int_as_float(e0.y);
        float v1 = __int_as_float(e1.y);
        long o0 = ((long)e0.x << 6) + l;
        long o1 = ((long)e1.x << 6) + l;
        const float4 xa0 = *reinterpret_cast<const float4*>(xA + o0);
        const float4 xa1 = *reinterpret_cast<const float4*>(xA + o1);
        const float4 xb0 = *reinterpret_cast<const float4*>(xB + o0);
        const float4 xb1 = *reinterpret_cast<const float4*>(xB + o1);
        fma4(pA0, v0, xa0);
        fma4(pA1, v1, xa1);
        fma4(pB0, v0, xb0);
        fma4(pB1, v1, xb1);
    }
    if (j < e){
        int2 e0 = csr[j];
        float v0 = __int_as_float(e0.y);
        long o0 = ((long)e0.x << 6) + l;
        const float4 xa0 = *reinterpret_cast<const float4*>(xA + o0);
        const float4 xb0 = *reinterpret_cast<const float4*>(xB + o0);
        fma4(pA0, v0, xa0);
        fma4(pB0, v0, xb0);
    }
    pA0.x += pA1.x; pA0.y += pA1.y; pA0.z += pA1.z; pA0.w += pA1.w;
    pB0.x += pB1.x; pB0.y += pB1.y; pB0.z += pB1.z; pB0.w += pB1.w;
    *reinterpret_cast<float4*>(yA + ((long)r << 6) + l) = pA0;
    *reinterpret_cast<float4*>(yB + ((long)r << 6) + l) = pB0;
}

// ---------------- attention fusion, register-tiled ----------------
__global__ __launch_bounds__(256) void k_fuse(const float* __restrict__ img,
        const float* __restrict__ txt, const float* __restrict__ W1,
        const float* __restrict__ b1, const float* __restrict__ w2,
        float* __restrict__ out){
    __shared__ float si[64][68];
    __shared__ float st[64][68];
    __shared__ float w1s[64][64];
    const int t  = threadIdx.x;
    const int tr = t >> 4;          // 0..15
    const int tc = t & 15;          // 0..15
    const long row0 = (long)blockIdx.x * 64;

#pragma unroll
    for (int i = 0; i < 4; ++i){
        int r = tr + 16 * i;
        *reinterpret_cast<float4*>(&si[r][tc * 4]) =
            *reinterpret_cast<const float4*>(img + (row0 + r) * 64 + tc * 4);
        *reinterpret_cast<float4*>(&st[r][tc * 4]) =
            *reinterpret_cast<const float4*>(txt + (row0 + r) * 64 + tc * 4);
    }
    {
        const float4* wsrc = reinterpret_cast<const float4*>(W1);
        float4* wdst = reinterpret_cast<float4*>(&w1s[0][0]);
#pragma unroll
        for (int i = 0; i < 4; ++i) wdst[t + 256 * i] = wsrc[t + 256 * i];
    }
    __syncthreads();

    float ai[4][4], at[4][4];
#pragma unroll
    for (int i = 0; i < 4; ++i)
#pragma unroll
        for (int j = 0; j < 4; ++j){ ai[i][j] = 0.f; at[i][j] = 0.f; }

#pragma unroll 8
    for (int kk = 0; kk < 64; kk += 2){
        float4 b0 = *reinterpret_cast<const float4*>(&w1s[kk][tc * 4]);
        float4 b1v = *reinterpret_cast<const float4*>(&w1s[kk + 1][tc * 4]);
#pragma unroll
        for (int i = 0; i < 4; ++i){
            float2 a = *reinterpret_cast<const float2*>(&si[tr + 16 * i][kk]);
            float2 c = *reinterpret_cast<const float2*>(&st[tr + 16 * i][kk]);
            ai[i][0] = fmaf(a.x, b0.x, ai[i][0]);
            ai[i][1] = fmaf(a.x, b0.y, ai[i][1]);
            ai[i][2] = fmaf(a.x, b0.z, ai[i][2]);
            ai[i][3] = fmaf(a.x, b0.w, ai[i][3]);
            ai[i][0] = fmaf(a.y, b1v.x, ai[i][0]);
            ai[i][1] = fmaf(a.y, b1v.y, ai[i][1]);
            ai[i][2] = fmaf(a.y, b1v.z, ai[i][2]);
            ai[i][3] = fmaf(a.y, b1v.w, ai[i][3]);
            at[i][0] = fmaf(c.x, b0.x, at[i][0]);
            at[i][1] = fmaf(c.x, b0.y, at[i][1]);
            at[i][2] = fmaf(c.x, b0.z, at[i][2]);
            at[i][3] = fmaf(c.x, b0.w, at[i][3]);
            at[i][0] = fmaf(c.y, b1v.x, at[i][0]);
            at[i][1] = fmaf(c.y, b1v.y, at[i][1]);
            at[i][2] = fmaf(c.y, b1v.z, at[i][2]);
            at[i][3] = fmaf(c.y, b1v.w, at[i][3]);
        }
    }

    const float4 b14 = reinterpret_cast<const float4*>(b1)[tc];
    const float4 w24 = reinterpret_cast<const float4*>(w2)[tc];
    float pi[4], pt[4];
#pragma unroll
    for (int i = 0; i < 4; ++i){
        float hi0 = ai[i][0] + b14.x; hi0 = (hi0 >= 0.f) ? hi0 : 0.01f * hi0;
        float hi1 = ai[i][1] + b14.y; hi1 = (hi1 >= 0.f) ? hi1 : 0.01f * hi1;
        float hi2 = ai[i][2] + b14.z; hi2 = (hi2 >= 0.f) ? hi2 : 0.01f * hi2;
        float hi3 = ai[i][3] + b14.w; hi3 = (hi3 >= 0.f) ? hi3 : 0.01f * hi3;
        float ht0 = at[i][0] + b14.x; ht0 = (ht0 >= 0.f) ? ht0 : 0.01f * ht0;
        float ht1 = at[i][1] + b14.y; ht1 = (ht1 >= 0.f) ? ht1 : 0.01f * ht1;
        float ht2 = at[i][2] + b14.z; ht2 = (ht2 >= 0.f) ? ht2 : 0.01f * ht2;
        float ht3 = at[i][3] + b14.w; ht3 = (ht3 >= 0.f) ? ht3 : 0.01f * ht3;
        pi[i] = fmaf(hi0, w24.x, fmaf(hi1, w24.y, fmaf(hi2, w24.z, hi3 * w24.w)));
        pt[i] = fmaf(ht0, w24.x, fmaf(ht1, w24.y, fmaf(ht2, w24.z, ht3 * w24.w)));
    }
#pragma unroll
    for (int m = 1; m < 16; m <<= 1){
#pragma unroll
        for (int i = 0; i < 4; ++i){
            pi[i] += __shfl_xor(pi[i], m, 64);
            pt[i] += __shfl_xor(pt[i], m, 64);
        }
    }

    const long NTD = (long)NTOT * DIM;
#pragma unroll
    for (int i = 0; i < 4; ++i){
        int r = tr + 16 * i;
        float mx = fmaxf(pi[i], pt[i]);
        float ei = __expf(pi[i] - mx), et = __expf(pt[i] - mx);
        float inv = 1.f / (ei + et);
        float wi = ei * inv, wt = et * inv;
        const float4 ie = *reinterpret_cast<const float4*>(&si[r][tc * 4]);
        const float4 te = *reinterpret_cast<const float4*>(&st[r][tc * 4]);
        float4 cm, oi, ot;
        cm.x = wi * ie.x + wt * te.x;
        cm.y = wi * ie.y + wt * te.y;
        cm.z = wi * ie.z + wt * te.z;
        cm.w = wi * ie.w + wt * te.w;
        oi.x = ie.x - cm.x; oi.y = ie.y - cm.y; oi.z = ie.z - cm.z; oi.w = ie.w - cm.w;
        ot.x = te.x - cm.x; ot.y = te.y - cm.y; ot.z = te.z - cm.z; ot.w = te.w - cm.w;
        long o = (row0 + r) * 64 + tc * 4;
        *reinterpret_cast<float4*>(out + NTD + o)     = oi;
        *reinterpret_cast<float4*>(out + 2 * NTD + o) = ot;
        *reinterpret_cast<float4*>(out + 3 * NTD + o) = cm;
    }
}

extern "C" void kernel_launch(void* const* d_in, const int* in_sizes, int n_in,
                              void* d_out, int out_size, void* d_ws, size_t ws_size,
                              hipStream_t stream){
    const float* user_emb  = (const float*)d_in[0];
    const float* item_emb  = (const float*)d_in[1];
    const float* image_emb = (const float*)d_in[2];
    const float* text_emb  = (const float*)d_in[3];
    const float* W_img = (const float*)d_in[4];
    const float* b_img = (const float*)d_in[5];
    const float* g_img = (const float*)d_in[6];
    const float* be_img= (const float*)d_in[7];
    const float* W_txt = (const float*)d_in[8];
    const float* b_txt = (const float*)d_in[9];
    const float* g_txt = (const float*)d_in[10];
    const float* be_txt= (const float*)d_in[11];
    const float* W_gi  = (const float*)d_in[12];
    const float* b_gi  = (const float*)d_in[13];
    const float* W_gt  = (const float*)d_in[14];
    const float* b_gt  = (const float*)d_in[15];
    const float* W_c1  = (const float*)d_in[16];
    const float* b_c1  = (const float*)d_in[17];
    const float* w_c2  = (const float*)d_in[18];
    const float* ui_vals = (const float*)d_in[19];
    const float* R_vals  = (const float*)d_in[20];
    const float* ii_iv   = (const float*)d_in[21];
    const float* ii_tv   = (const float*)d_in[22];
    const int* ui_rows = (const int*)d_in[23];
    const int* ui_cols = (const int*)d_in[24];
    const int* R_rows  = (const int*)d_in[25];
    const int* R_cols  = (const int*)d_in[26];
    const int* ii_ir   = (const int*)d_in[27];
    const int* ii_ic   = (const int*)d_in[28];
    const int* ii_tr   = (const int*)d_in[29];
    const int* ii_tc   = (const int*)d_in[30];

    const long ND = (long)NTOT * DIM;    // 5,120,000
    const long ID = (long)N_ITEM * DIM;  // 1,920,000
    const long UD = (long)N_USER * DIM;  // 3,200,000

    float* out = (float*)d_out;
    float* o0 = out;
    float* o1 = out + ND;
    float* o2 = out + 2 * ND;
    float* o3 = out + 3 * ND;

    // projgate outputs in o3 (dead until modal hop-2 overwrites)
    float* P_img = o3;
    float* P_txt = o3 + ID;
    // modal hop-1 outputs in o1 (o1 fully dead until pullRC): 2*ID < ND
    float* Q_img = o1;
    float* Q_txt = o1 + ID;
    // modal hop-2 outputs back into o3 (P dead after hop-1)
    float* H_img = o3;
    float* H_txt = o3 + ID;

    // binned staging (19.2 MB) lives in o0 — dead after k_scatter.
    int2* binned = (int2*)o0;

    // ---- workspace (~20 MB): combined CSR + bucket tables ----
    int2* csr   = (int2*)d_ws;                  // NNZ_ALL (19.2 MB)
    int*  off   = (int*)(csr + NNZ_ALL);        // NROWS_ALL + 1 (+pad)
    int*  bcnt  = off + NROWS_ALL + 4;          // NBUCK
    int*  bcur  = bcnt + NBUCK;                 // NBUCK (adjacent: one memset)
    int*  bbase = bcur + NBUCK;                 // NBUCK + 1

    // ---- build combined CSR: fused cooperative hist+scan+bin, then scatter ----
    hipMemsetAsync(bcnt, 0, 2 * NBUCK * sizeof(int), stream);   // bcnt + bcur
    {
        void* args[] = {
            (void*)&ui_rows, (void*)&ui_cols, (void*)&ui_vals,
            (void*)&R_rows,  (void*)&R_cols,  (void*)&R_vals,
            (void*)&ii_ir,   (void*)&ii_ic,   (void*)&ii_iv,
            (void*)&ii_tr,   (void*)&ii_tc,   (void*)&ii_tv,
            (void*)&bcnt, (void*)&bbase, (void*)&off, (void*)&bcur, (void*)&binned
        };
        hipLaunchCooperativeKernel(reinterpret_cast<void*>(k_build123),
                                   dim3(NBLK_A2), dim3(256), args, 0, stream);
    }
    k_scatter<<<NBUCK, 256, 0, stream>>>(bbase, binned, off, csr);

    const int* offUI = off;
    const int* offR  = off + BASE_R;
    const int* offI2 = off + BASE_II;
    const int* offT2 = off + BASE_IT;

    // ---- MEGA1: projgate first (round-8 body), UI hop-1 pulls behind ----
    k_mega1<<<NBLK_M1, 256, 0, stream>>>(
        offUI, csr, user_emb, o2,
        image_emb, W_img, b_img, g_img, be_img, W_gi, b_gi,
        text_emb,  W_txt, b_txt, g_txt, be_txt, W_gt, b_gt,
        item_emb, P_img, P_txt);

    // ---- MEGA2 (contiguous): UI hop-2 + mean (o2 -> o0), modal hop-1 (P -> Q)
    k_mega2c<<<NBLK_M2, 256, 0, stream>>>(
        offUI, csr, o2, item_emb, user_emb, o0,
        offI2, P_img, Q_img, offT2, P_txt, Q_txt);
    // o2 free from here; P dead (consumed by hop-1)

    // ---- modal hop-2: Q (o1) -> H (o3) ----
    k_pull2<<<2 * NBLK_I16, 256, 0, stream>>>(
        offI2, csr, Q_img, H_img, offT2, Q_txt, H_txt, N_ITEM, NBLK_I16);
    // Q dead; o1 free

    // ---- R-pull both modalities + item-block copies (o3 -> o1/o2 tails) ----
    k_pullRC<<<NBLK_RC, 256, 0, stream>>>(
        offR, csr, H_img, o1, H_txt, o2, o1 + UD, o2 + UD);

    // ---- fusion epilogue (reads o1/o2, writes o1/o2/o3) ----
    k_fuse<<<NTOT / 64, 256, 0, stream>>>(o1, o2, W_c1, b_c1, w_c2, out);
}

// Round 11
// 550.084 us; speedup vs baseline: 1.1978x; 1.1978x over previous
//
#include <hip/hip_runtime.h>

#define N_USER 50000
#define N_ITEM 30000
#define DIM    64
#define NTOT   80000
#define NNZ_UI 1000000
#define NNZ_R  800000
#define NNZ_II 300000
#define IMG_F  512
#define TXT_F  384

#define NROWS_ALL 190000            // NTOT + N_USER + N_ITEM + N_ITEM
#define NNZ_ALL   2400000           // NNZ_UI + NNZ_R + 2*NNZ_II
#define BASE_R    NTOT              // 80000
#define BASE_II   (NTOT + N_USER)   // 130000
#define BASE_IT   (NTOT + N_USER + N_ITEM) // 160000

// row-bucketed CSR build: 512 rows per bucket
#define RB_BITS   9
#define RB_ROWS   512
#define NBUCK     ((NROWS_ALL + RB_ROWS - 1) / RB_ROWS)   // 372
#define NBLK_A2   400
#define EDG_A2    6000              // 400 * 6000 == NNZ_ALL exactly

#define NBLK_PG   625               // N_ITEM / 48
#define NBLK_UIP  5000              // NTOT*16/256
#define NBLK_I16  1875              // N_ITEM*16/256
#define NBLK_U16  3125              // N_USER*16/256
#define NBLK_CP   1875              // N_ITEM*DIM/1024 float4-copy blocks

#define NBLK_M1   (2 * NBLK_PG + NBLK_UIP)          // 6250, projgate FIRST
#define NBLK_M2   (NBLK_UIP + 2 * NBLK_I16)         // 8750, pull_mean first
#define NBLK_RC   (NBLK_U16 + 2 * NBLK_CP)          // 6875

// ---------------- edge decode helpers (fused 4-list view) ----------------
__device__ __forceinline__ int edge_row(int i,
        const int* __restrict__ r0, const int* __restrict__ r1,
        const int* __restrict__ r2, const int* __restrict__ r3){
    if (i < NNZ_UI)                       return r0[i];
    if (i < NNZ_UI + NNZ_R)               return BASE_R  + r1[i - NNZ_UI];
    if (i < NNZ_UI + NNZ_R + NNZ_II)      return BASE_II + r2[i - NNZ_UI - NNZ_R];
    return BASE_IT + r3[i - NNZ_UI - NNZ_R - NNZ_II];
}

__device__ __forceinline__ void edge_all(int i,
        const int* __restrict__ r0, const int* __restrict__ c0, const float* __restrict__ v0,
        const int* __restrict__ r1, const int* __restrict__ c1, const float* __restrict__ v1,
        const int* __restrict__ r2, const int* __restrict__ c2, const float* __restrict__ v2,
        const int* __restrict__ r3, const int* __restrict__ c3, const float* __restrict__ v3,
        int& gr, int& col, float& val){
    if (i < NNZ_UI){
        gr = r0[i]; col = c0[i]; val = v0[i];
    } else if (i < NNZ_UI + NNZ_R){
        int j = i - NNZ_UI;               gr = BASE_R  + r1[j]; col = c1[j]; val = v1[j];
    } else if (i < NNZ_UI + NNZ_R + NNZ_II){
        int j = i - NNZ_UI - NNZ_R;       gr = BASE_II + r2[j]; col = c2[j]; val = v2[j];
    } else {
        int j = i - NNZ_UI - NNZ_R - NNZ_II; gr = BASE_IT + r3[j]; col = c3[j]; val = v3[j];
    }
}

// ---------------- build 1: bucket histogram (LDS-aggregated) ----------------
__global__ __launch_bounds__(256) void k_bhist(const int* __restrict__ r0,
        const int* __restrict__ r1, const int* __restrict__ r2,
        const int* __restrict__ r3, int* __restrict__ bcnt){
    __shared__ int h[NBUCK];
    for (int i = threadIdx.x; i < NBUCK; i += 256) h[i] = 0;
    __syncthreads();
    const int stride = gridDim.x * 256;
    for (int i = blockIdx.x * 256 + threadIdx.x; i < NNZ_ALL; i += stride){
        int gr = edge_row(i, r0, r1, r2, r3);
        atomicAdd(&h[gr >> RB_BITS], 1);
    }
    __syncthreads();
    for (int i = threadIdx.x; i < NBUCK; i += 256){
        int c = h[i];
        if (c) atomicAdd(&bcnt[i], c);
    }
}

// ---------------- build 2: scan bucket counts (single block) ----------------
__global__ __launch_bounds__(512) void k_bscan(const int* __restrict__ bcnt,
        int* __restrict__ bbase, int* __restrict__ off){
    __shared__ int sh[512];
    const int t = threadIdx.x;
    int v = (t < NBUCK) ? bcnt[t] : 0;
    sh[t] = v;
    __syncthreads();
    for (int d = 1; d < 512; d <<= 1){
        int u = (t >= d) ? sh[t - d] : 0;
        __syncthreads();
        sh[t] += u;
        __syncthreads();
    }
    if (t < NBUCK) bbase[t] = sh[t] - v;          // exclusive prefix
    if (t == NBUCK - 1){
        bbase[NBUCK] = sh[t];                      // grand total (== NNZ_ALL)
        off[NROWS_ALL] = sh[t];
    }
}

// ---------------- build 3: bin edges into bucket-major staging ----------------
__global__ __launch_bounds__(256) void k_bin(
        const int* __restrict__ r0, const int* __restrict__ c0, const float* __restrict__ v0,
        const int* __restrict__ r1, const int* __restrict__ c1, const float* __restrict__ v1,
        const int* __restrict__ r2, const int* __restrict__ c2, const float* __restrict__ v2,
        const int* __restrict__ r3, const int* __restrict__ c3, const float* __restrict__ v3,
        const int* __restrict__ bbase, int* __restrict__ bcur,
        int2* __restrict__ binned){
    __shared__ int lofs[NBUCK];
    __shared__ int lcur[NBUCK];
    const int t = threadIdx.x;
    for (int i = t; i < NBUCK; i += 256){ lofs[i] = 0; lcur[i] = 0; }
    __syncthreads();
    const int s0 = blockIdx.x * EDG_A2, s1 = s0 + EDG_A2;
    for (int i = s0 + t; i < s1; i += 256){
        int gr = edge_row(i, r0, r1, r2, r3);
        atomicAdd(&lofs[gr >> RB_BITS], 1);
    }
    __syncthreads();
    for (int i = t; i < NBUCK; i += 256){
        int c = lofs[i];
        lofs[i] = c ? (bbase[i] + atomicAdd(&bcur[i], c)) : 0;
    }
    __syncthreads();
    for (int i = s0 + t; i < s1; i += 256){
        int gr, col; float val;
        edge_all(i, r0, c0, v0, r1, c1, v1, r2, c2, v2, r3, c3, v3, gr, col, val);
        int b = gr >> RB_BITS;
        int slot = atomicAdd(&lcur[b], 1);
        binned[lofs[b] + slot] = make_int2((col << RB_BITS) | (gr & (RB_ROWS - 1)),
                                           __float_as_int(val));
    }
}

// ---------------- build 4: per-bucket hist+scan+scatter (one block = one bucket)
__global__ __launch_bounds__(256) void k_scatter(const int* __restrict__ bbase,
        const int2* __restrict__ binned, int* __restrict__ off,
        int2* __restrict__ csr){
    __shared__ int h[RB_ROWS];
    const int t = threadIdx.x;
    const int b = blockIdx.x;
    const int base = bbase[b];
    const int nb = bbase[b + 1] - base;
    h[t] = 0; h[t + 256] = 0;
    __syncthreads();
    for (int i = t; i < nb; i += 256)
        atomicAdd(&h[binned[base + i].x & (RB_ROWS - 1)], 1);
    __syncthreads();
    if (t < 64){
        int v[8], s = 0;
#pragma unroll
        for (int k = 0; k < 8; ++k){ v[k] = h[t * 8 + k]; s += v[k]; }
        int incl = s;
#pragma unroll
        for (int d = 1; d < 64; d <<= 1){
            int u = __shfl_up(incl, d, 64);
            if (t >= d) incl += u;
        }
        int run = incl - s;
#pragma unroll
        for (int k = 0; k < 8; ++k){ int tmp = v[k]; h[t * 8 + k] = run; run += tmp; }
    }
    __syncthreads();
    const int row0 = b << RB_BITS;
    for (int i = t; i < RB_ROWS; i += 256){
        int r = row0 + i;
        if (r < NROWS_ALL) off[r] = base + h[i];
    }
    __syncthreads();
    for (int i = t; i < nb; i += 256){
        int2 rec = binned[base + i];
        int lr = rec.x & (RB_ROWS - 1);
        int slot = atomicAdd(&h[lr], 1);
        csr[base + slot] = make_int2(rec.x >> RB_BITS, rec.y);
    }
}

// ---------------- virtual cat = [item_emb; user_emb] row pointer ----------------
__device__ __forceinline__ const float* cat_row(int c,
        const float* __restrict__ item, const float* __restrict__ user){
    return (c < N_ITEM) ? (item + ((long)c << 6)) : (user + ((long)(c - N_ITEM) << 6));
}

// fma helper
__device__ __forceinline__ void fma4(float4& a, float v, const float4& x){
    a.x = fmaf(v, x.x, a.x);
    a.y = fmaf(v, x.y, a.y);
    a.z = fmaf(v, x.z, a.z);
    a.w = fmaf(v, x.w, a.w);
}

// ---------------- pull-SpMM body (2-deep: 2 gathers in flight) ----------------
__device__ __forceinline__ void pull_body(const int* __restrict__ off,
        const int2* __restrict__ csr, const float* __restrict__ x,
        float* __restrict__ y, int r, int l){
    int s = off[r], e = off[r + 1];
    float4 a0 = {0.f, 0.f, 0.f, 0.f};
    float4 a1 = {0.f, 0.f, 0.f, 0.f};
    int j = s;
    for (; j + 2 <= e; j += 2){
        int2 e0 = csr[j];
        int2 e1 = csr[j + 1];
        const float4 x0 = *reinterpret_cast<const float4*>(x + ((long)e0.x << 6) + l);
        const float4 x1 = *reinterpret_cast<const float4*>(x + ((long)e1.x << 6) + l);
        fma4(a0, __int_as_float(e0.y), x0);
        fma4(a1, __int_as_float(e1.y), x1);
    }
    if (j < e){
        int2 e0 = csr[j];
        const float4 x0 = *reinterpret_cast<const float4*>(x + ((long)e0.x << 6) + l);
        fma4(a0, __int_as_float(e0.y), x0);
    }
    a0.x += a1.x; a0.y += a1.y; a0.z += a1.z; a0.w += a1.w;
    *reinterpret_cast<float4*>(y + ((long)r << 6) + l) = a0;
}

// pull body over the virtual cat (UI hop 1; no cat0 materialization)
__device__ __forceinline__ void pull_cat_body(const int* __restrict__ off,
        const int2* __restrict__ csr, const float* __restrict__ item,
        const float* __restrict__ user, float* __restrict__ y, int r, int l){
    int s = off[r], e = off[r + 1];
    float4 a0 = {0.f, 0.f, 0.f, 0.f};
    float4 a1 = {0.f, 0.f, 0.f, 0.f};
    int j = s;
    for (; j + 2 <= e; j += 2){
        int2 e0 = csr[j];
        int2 e1 = csr[j + 1];
        const float4 x0 = *reinterpret_cast<const float4*>(cat_row(e0.x, item, user) + l);
        const float4 x1 = *reinterpret_cast<const float4*>(cat_row(e1.x, item, user) + l);
        fma4(a0, __int_as_float(e0.y), x0);
        fma4(a1, __int_as_float(e1.y), x1);
    }
    if (j < e){
        int2 e0 = csr[j];
        const float4 x0 = *reinterpret_cast<const float4*>(cat_row(e0.x, item, user) + l);
        fma4(a0, __int_as_float(e0.y), x0);
    }
    a0.x += a1.x; a0.y += a1.y; a0.z += a1.z; a0.w += a1.w;
    *reinterpret_cast<float4*>(y + ((long)r << 6) + l) = a0;
}

// UI hop-2 + content mean body: o0[r] = (cat_row(r) + x[r] + pull(x)[r]) / 3
__device__ __forceinline__ void pull_mean_body(const int* __restrict__ off,
        const int2* __restrict__ csr, const float* __restrict__ x,
        const float* __restrict__ item, const float* __restrict__ user,
        float* __restrict__ o0, int r, int l){
    int s = off[r], e = off[r + 1];
    float4 a0 = {0.f, 0.f, 0.f, 0.f};
    float4 a1 = {0.f, 0.f, 0.f, 0.f};
    int j = s;
    for (; j + 2 <= e; j += 2){
        int2 e0 = csr[j];
        int2 e1 = csr[j + 1];
        const float4 x0 = *reinterpret_cast<const float4*>(x + ((long)e0.x << 6) + l);
        const float4 x1 = *reinterpret_cast<const float4*>(x + ((long)e1.x << 6) + l);
        fma4(a0, __int_as_float(e0.y), x0);
        fma4(a1, __int_as_float(e1.y), x1);
    }
    if (j < e){
        int2 e0 = csr[j];
        const float4 x0 = *reinterpret_cast<const float4*>(x + ((long)e0.x << 6) + l);
        fma4(a0, __int_as_float(e0.y), x0);
    }
    a0.x += a1.x; a0.y += a1.y; a0.z += a1.z; a0.w += a1.w;
    const float4 av = *reinterpret_cast<const float4*>(cat_row(r, item, user) + l);
    const float4 xv = *reinterpret_cast<const float4*>(x + ((long)r << 6) + l);
    float4 o;
    o.x = (av.x + xv.x + a0.x) * (1.0f / 3.0f);
    o.y = (av.y + xv.y + a0.y) * (1.0f / 3.0f);
    o.z = (av.z + xv.z + a0.z) * (1.0f / 3.0f);
    o.w = (av.w + xv.w + a0.w) * (1.0f / 3.0f);
    *reinterpret_cast<float4*>(o0 + ((long)r << 6) + l) = o;
}

// two independent pulls in one launch (same nrows for both halves)
__global__ void k_pull2(const int* __restrict__ offA, const int2* __restrict__ csr,
                        const float* __restrict__ xA, float* __restrict__ yA,
                        const int* __restrict__ offB, const float* __restrict__ xB,
                        float* __restrict__ yB, int nrows, int nblk_half){
    int b = blockIdx.x;
    const int* off; const float* x; float* y;
    if (b < nblk_half){ off = offA; x = xA; y = yA; }
    else              { b -= nblk_half; off = offB; x = xB; y = yB; }
    int t = b * 256 + threadIdx.x;
    int r = t >> 4;
    if (r >= nrows) return;
    pull_body(off, csr, x, y, r, (t & 15) << 2);
}

// ---------------- MEGA1: projgate FIRST, then UI-hop1 pulls (contiguous) ------
// blocks [0,1250): projgate (img then txt); blocks [1250,6250): UI hop-1 pull.
// Long-latency VALU blocks dispatch first; pull blocks fill in behind them.
__global__ __launch_bounds__(256) void k_mega1(
        const int* __restrict__ offUI, const int2* __restrict__ csr,
        const float* __restrict__ user,
        float* __restrict__ hop1out,
        const float* __restrict__ Xi, const float* __restrict__ Wi,
        const float* __restrict__ bi, const float* __restrict__ gi,
        const float* __restrict__ bei, const float* __restrict__ Wgi,
        const float* __restrict__ bgi,
        const float* __restrict__ Xt, const float* __restrict__ Wt,
        const float* __restrict__ bt, const float* __restrict__ gt,
        const float* __restrict__ bet, const float* __restrict__ Wgt,
        const float* __restrict__ bgt,
        const float* __restrict__ item,
        float* __restrict__ Pi, float* __restrict__ Pt){
    __shared__ float xs[48][68];    // +4 pad: conflict-free, f4-aligned
    __shared__ float ws[64][64];

    if (blockIdx.x >= 2 * NBLK_PG){
        // ---- UI hop-1 pull path (5000 blocks; exact: r < NTOT) ----
        int pb = blockIdx.x - 2 * NBLK_PG;
        int t = pb * 256 + threadIdx.x;
        int r = t >> 4;
        pull_cat_body(offUI, csr, item, user, hop1out, r, (t & 15) << 2);
        return;
    }

    // ---- projgate path (1250 blocks) ----
    const int t  = threadIdx.x;
    const int tr = t >> 4;          // 0..15
    const int tc = t & 15;          // 0..15
    const int pgb = blockIdx.x;
    const bool isTxt = pgb >= NBLK_PG;
    const int  blk   = isTxt ? (pgb - NBLK_PG) : pgb;
    const int  K     = isTxt ? TXT_F : IMG_F;
    const float* X   = isTxt ? Xt  : Xi;
    const float* W   = isTxt ? Wt  : Wi;
    const float* bb  = isTxt ? bt  : bi;
    const float* gg  = isTxt ? gt  : gi;
    const float* be  = isTxt ? bet : bei;
    const float* Wg  = isTxt ? Wgt : Wgi;
    const float* bg  = isTxt ? bgt : bgi;
    float* outP      = isTxt ? Pt  : Pi;
    const int row0   = blk * 48;

    float acc[3][4];
#pragma unroll
    for (int i = 0; i < 3; ++i)
#pragma unroll
        for (int j = 0; j < 4; ++j) acc[i][j] = 0.f;

    for (int ks = 0; ks < K; ks += 64){
        __syncthreads();
        // stage X tile [48][64]
#pragma unroll
        for (int i = 0; i < 3; ++i){
            int r = tr + 16 * i;
            *reinterpret_cast<float4*>(&xs[r][tc * 4]) =
                *reinterpret_cast<const float4*>(X + (long)(row0 + r) * K + ks + tc * 4);
        }
        // stage W tile [64][64] (contiguous 16 KB)
        {
            const float4* wsrc = reinterpret_cast<const float4*>(W + (long)ks * 64);
            float4* wdst = reinterpret_cast<float4*>(&ws[0][0]);
#pragma unroll
            for (int i = 0; i < 4; ++i) wdst[t + 256 * i] = wsrc[t + 256 * i];
        }
        __syncthreads();
#pragma unroll 8
        for (int kk = 0; kk < 64; kk += 2){
            float2 a[3];
#pragma unroll
            for (int i = 0; i < 3; ++i)
                a[i] = *reinterpret_cast<const float2*>(&xs[tr + 16 * i][kk]);
            float4 b0 = *reinterpret_cast<const float4*>(&ws[kk][tc * 4]);
            float4 b1 = *reinterpret_cast<const float4*>(&ws[kk + 1][tc * 4]);
#pragma unroll
            for (int i = 0; i < 3; ++i){
                acc[i][0] = fmaf(a[i].x, b0.x, acc[i][0]);
                acc[i][1] = fmaf(a[i].x, b0.y, acc[i][1]);
                acc[i][2] = fmaf(a[i].x, b0.z, acc[i][2]);
                acc[i][3] = fmaf(a[i].x, b0.w, acc[i][3]);
                acc[i][0] = fmaf(a[i].y, b1.x, acc[i][0]);
                acc[i][1] = fmaf(a[i].y, b1.y, acc[i][1]);
                acc[i][2] = fmaf(a[i].y, b1.z, acc[i][2]);
                acc[i][3] = fmaf(a[i].y, b1.w, acc[i][3]);
            }
        }
    }

    // ---- epilogue 1: feat = leaky(BN(acc + b)) -> xs; stage Wg -> ws ----
    const float4 b4  = reinterpret_cast<const float4*>(bb)[tc];
    const float4 g4  = reinterpret_cast<const float4*>(gg)[tc];
    const float4 be4 = reinterpret_cast<const float4*>(be)[tc];
    __syncthreads();    // all reads of xs/ws done
#pragma unroll
    for (int i = 0; i < 3; ++i){
        int r = tr + 16 * i;
        float4 h;
        h.x = (acc[i][0] + b4.x) * (g4.x * 0.99999500003749943f) + be4.x;
        h.y = (acc[i][1] + b4.y) * (g4.y * 0.99999500003749943f) + be4.y;
        h.z = (acc[i][2] + b4.z) * (g4.z * 0.99999500003749943f) + be4.z;
        h.w = (acc[i][3] + b4.w) * (g4.w * 0.99999500003749943f) + be4.w;
        h.x = (h.x >= 0.f) ? h.x : 0.01f * h.x;
        h.y = (h.y >= 0.f) ? h.y : 0.01f * h.y;
        h.z = (h.z >= 0.f) ? h.z : 0.01f * h.z;
        h.w = (h.w >= 0.f) ? h.w : 0.01f * h.w;
        *reinterpret_cast<float4*>(&xs[r][tc * 4]) = h;
    }
    {
        const float4* wsrc = reinterpret_cast<const float4*>(Wg);
        float4* wdst = reinterpret_cast<float4*>(&ws[0][0]);
#pragma unroll
        for (int i = 0; i < 4; ++i) wdst[t + 256 * i] = wsrc[t + 256 * i];
    }
    __syncthreads();

    // ---- gate GEMM: feat @ Wg (K = 64) ----
    float ac2[3][4];
#pragma unroll
    for (int i = 0; i < 3; ++i)
#pragma unroll
        for (int j = 0; j < 4; ++j) ac2[i][j] = 0.f;
#pragma unroll 8
    for (int kk = 0; kk < 64; kk += 2){
        float2 a[3];
#pragma unroll
        for (int i = 0; i < 3; ++i)
            a[i] = *reinterpret_cast<const float2*>(&xs[tr + 16 * i][kk]);
        float4 b0 = *reinterpret_cast<const float4*>(&ws[kk][tc * 4]);
        float4 b1 = *reinterpret_cast<const float4*>(&ws[kk + 1][tc * 4]);
#pragma unroll
        for (int i = 0; i < 3; ++i){
            ac2[i][0] = fmaf(a[i].x, b0.x, ac2[i][0]);
            ac2[i][1] = fmaf(a[i].x, b0.y, ac2[i][1]);
            ac2[i][2] = fmaf(a[i].x, b0.z, ac2[i][2]);
            ac2[i][3] = fmaf(a[i].x, b0.w, ac2[i][3]);
            ac2[i][0] = fmaf(a[i].y, b1.x, ac2[i][0]);
            ac2[i][1] = fmaf(a[i].y, b1.y, ac2[i][1]);
            ac2[i][2] = fmaf(a[i].y, b1.z, ac2[i][2]);
            ac2[i][3] = fmaf(a[i].y, b1.w, ac2[i][3]);
        }
    }

    // ---- epilogue 2: P = item * sigmoid(ac2 + bg) ----
    const float4 bg4 = reinterpret_cast<const float4*>(bg)[tc];
#pragma unroll
    for (int i = 0; i < 3; ++i){
        int r = tr + 16 * i;
        const float4 iv = *reinterpret_cast<const float4*>(
                item + (long)(row0 + r) * 64 + tc * 4);
        float4 o;
        o.x = iv.x / (1.f + __expf(-(ac2[i][0] + bg4.x)));
        o.y = iv.y / (1.f + __expf(-(ac2[i][1] + bg4.y)));
        o.z = iv.z / (1.f + __expf(-(ac2[i][2] + bg4.z)));
        o.w = iv.w / (1.f + __expf(-(ac2[i][3] + bg4.w)));
        *reinterpret_cast<float4*>(outP + (long)(row0 + r) * 64 + tc * 4) = o;
    }
}

// ---------------- MEGA2: UI hop-2 + mean, then modal hop-1 (CONTIGUOUS) -------
__global__ void k_mega2c(const int* __restrict__ offUI, const int2* __restrict__ csr,
        const float* __restrict__ hop1,         // o2 (read-only here)
        const float* __restrict__ item, const float* __restrict__ user,
        float* __restrict__ o0,
        const int* __restrict__ offI2, const float* __restrict__ P_img,
        float* __restrict__ Q_img,
        const int* __restrict__ offT2, const float* __restrict__ P_txt,
        float* __restrict__ Q_txt){
    const int tid = threadIdx.x;
    if (blockIdx.x < NBLK_UIP){
        int t = blockIdx.x * 256 + tid;
        int r = t >> 4;                         // exact: r < NTOT
        pull_mean_body(offUI, csr, hop1, item, user, o0, r, (t & 15) << 2);
    } else {
        int m = blockIdx.x - NBLK_UIP;          // 0..3750
        const int* off; const float* x; float* y;
        if (m < NBLK_I16){ off = offI2; x = P_img; y = Q_img; }
        else             { m -= NBLK_I16; off = offT2; x = P_txt; y = Q_txt; }
        int t = m * 256 + tid;
        int r = t >> 4;                         // exact: r < N_ITEM
        pull_body(off, csr, x, y, r, (t & 15) << 2);
    }
}

// ---------------- pullR + item-block copies in one launch ----------------
__global__ void k_pullRC(const int* __restrict__ off, const int2* __restrict__ csr,
                         const float* __restrict__ xA, float* __restrict__ yA,
                         const float* __restrict__ xB, float* __restrict__ yB,
                         float* __restrict__ dA, float* __restrict__ dB){
    int bid = blockIdx.x;
    const int tid = threadIdx.x;
    if (bid >= NBLK_U16){
        int c = bid - NBLK_U16;
        const float4* src; float4* dst;
        if (c < NBLK_CP){ src = reinterpret_cast<const float4*>(xA);
                          dst = reinterpret_cast<float4*>(dA); }
        else { c -= NBLK_CP; src = reinterpret_cast<const float4*>(xB);
               dst = reinterpret_cast<float4*>(dB); }
        int i = c * 256 + tid;                  // 480000 float4 per block set
        dst[i] = src[i];
        return;
    }
    int t = bid * 256 + tid;
    int r = t >> 4;                             // exact: r < N_USER
    int l = (t & 15) << 2;
    int s = off[r], e = off[r + 1];
    float4 pA0 = {0.f,0.f,0.f,0.f}, pA1 = {0.f,0.f,0.f,0.f};
    float4 pB0 = {0.f,0.f,0.f,0.f}, pB1 = {0.f,0.f,0.f,0.f};
    int j = s;
    for (; j + 2 <= e; j += 2){
        int2 e0 = csr[j];
        int2 e1 = csr[j + 1];
        float v0 = __int_as_float(e0.y);
        float v1 = __int_as_float(e1.y);
        long o0 = ((long)e0.x << 6) + l;
        long o1 = ((long)e1.x << 6) + l;
        const float4 xa0 = *reinterpret_cast<const float4*>(xA + o0);
        const float4 xa1 = *reinterpret_cast<const float4*>(xA + o1);
        const float4 xb0 = *reinterpret_cast<const float4*>(xB + o0);
        const float4 xb1 = *reinterpret_cast<const float4*>(xB + o1);
        fma4(pA0, v0, xa0);
        fma4(pA1, v1, xa1);
        fma4(pB0, v0, xb0);
        fma4(pB1, v1, xb1);
    }
    if (j < e){
        int2 e0 = csr[j];
        float v0 = __int_as_float(e0.y);
        long o0 = ((long)e0.x << 6) + l;
        const float4 xa0 = *reinterpret_cast<const float4*>(xA + o0);
        const float4 xb0 = *reinterpret_cast<const float4*>(xB + o0);
        fma4(pA0, v0, xa0);
        fma4(pB0, v0, xb0);
    }
    pA0.x += pA1.x; pA0.y += pA1.y; pA0.z += pA1.z; pA0.w += pA1.w;
    pB0.x += pB1.x; pB0.y += pB1.y; pB0.z += pB1.z; pB0.w += pB1.w;
    *reinterpret_cast<float4*>(yA + ((long)r << 6) + l) = pA0;
    *reinterpret_cast<float4*>(yB + ((long)r << 6) + l) = pB0;
}

// ---------------- attention fusion, register-tiled ----------------
__global__ __launch_bounds__(256) void k_fuse(const float* __restrict__ img,
        const float* __restrict__ txt, const float* __restrict__ W1,
        const float* __restrict__ b1, const float* __restrict__ w2,
        float* __restrict__ out){
    __shared__ float si[64][68];
    __shared__ float st[64][68];
    __shared__ float w1s[64][64];
    const int t  = threadIdx.x;
    const int tr = t >> 4;          // 0..15
    const int tc = t & 15;          // 0..15
    const long row0 = (long)blockIdx.x * 64;

#pragma unroll
    for (int i = 0; i < 4; ++i){
        int r = tr + 16 * i;
        *reinterpret_cast<float4*>(&si[r][tc * 4]) =
            *reinterpret_cast<const float4*>(img + (row0 + r) * 64 + tc * 4);
        *reinterpret_cast<float4*>(&st[r][tc * 4]) =
            *reinterpret_cast<const float4*>(txt + (row0 + r) * 64 + tc * 4);
    }
    {
        const float4* wsrc = reinterpret_cast<const float4*>(W1);
        float4* wdst = reinterpret_cast<float4*>(&w1s[0][0]);
#pragma unroll
        for (int i = 0; i < 4; ++i) wdst[t + 256 * i] = wsrc[t + 256 * i];
    }
    __syncthreads();

    float ai[4][4], at[4][4];
#pragma unroll
    for (int i = 0; i < 4; ++i)
#pragma unroll
        for (int j = 0; j < 4; ++j){ ai[i][j] = 0.f; at[i][j] = 0.f; }

#pragma unroll 8
    for (int kk = 0; kk < 64; kk += 2){
        float4 b0 = *reinterpret_cast<const float4*>(&w1s[kk][tc * 4]);
        float4 b1v = *reinterpret_cast<const float4*>(&w1s[kk + 1][tc * 4]);
#pragma unroll
        for (int i = 0; i < 4; ++i){
            float2 a = *reinterpret_cast<const float2*>(&si[tr + 16 * i][kk]);
            float2 c = *reinterpret_cast<const float2*>(&st[tr + 16 * i][kk]);
            ai[i][0] = fmaf(a.x, b0.x, ai[i][0]);
            ai[i][1] = fmaf(a.x, b0.y, ai[i][1]);
            ai[i][2] = fmaf(a.x, b0.z, ai[i][2]);
            ai[i][3] = fmaf(a.x, b0.w, ai[i][3]);
            ai[i][0] = fmaf(a.y, b1v.x, ai[i][0]);
            ai[i][1] = fmaf(a.y, b1v.y, ai[i][1]);
            ai[i][2] = fmaf(a.y, b1v.z, ai[i][2]);
            ai[i][3] = fmaf(a.y, b1v.w, ai[i][3]);
            at[i][0] = fmaf(c.x, b0.x, at[i][0]);
            at[i][1] = fmaf(c.x, b0.y, at[i][1]);
            at[i][2] = fmaf(c.x, b0.z, at[i][2]);
            at[i][3] = fmaf(c.x, b0.w, at[i][3]);
            at[i][0] = fmaf(c.y, b1v.x, at[i][0]);
            at[i][1] = fmaf(c.y, b1v.y, at[i][1]);
            at[i][2] = fmaf(c.y, b1v.z, at[i][2]);
            at[i][3] = fmaf(c.y, b1v.w, at[i][3]);
        }
    }

    const float4 b14 = reinterpret_cast<const float4*>(b1)[tc];
    const float4 w24 = reinterpret_cast<const float4*>(w2)[tc];
    float pi[4], pt[4];
#pragma unroll
    for (int i = 0; i < 4; ++i){
        float hi0 = ai[i][0] + b14.x; hi0 = (hi0 >= 0.f) ? hi0 : 0.01f * hi0;
        float hi1 = ai[i][1] + b14.y; hi1 = (hi1 >= 0.f) ? hi1 : 0.01f * hi1;
        float hi2 = ai[i][2] + b14.z; hi2 = (hi2 >= 0.f) ? hi2 : 0.01f * hi2;
        float hi3 = ai[i][3] + b14.w; hi3 = (hi3 >= 0.f) ? hi3 : 0.01f * hi3;
        float ht0 = at[i][0] + b14.x; ht0 = (ht0 >= 0.f) ? ht0 : 0.01f * ht0;
        float ht1 = at[i][1] + b14.y; ht1 = (ht1 >= 0.f) ? ht1 : 0.01f * ht1;
        float ht2 = at[i][2] + b14.z; ht2 = (ht2 >= 0.f) ? ht2 : 0.01f * ht2;
        float ht3 = at[i][3] + b14.w; ht3 = (ht3 >= 0.f) ? ht3 : 0.01f * ht3;
        pi[i] = fmaf(hi0, w24.x, fmaf(hi1, w24.y, fmaf(hi2, w24.z, hi3 * w24.w)));
        pt[i] = fmaf(ht0, w24.x, fmaf(ht1, w24.y, fmaf(ht2, w24.z, ht3 * w24.w)));
    }
#pragma unroll
    for (int m = 1; m < 16; m <<= 1){
#pragma unroll
        for (int i = 0; i < 4; ++i){
            pi[i] += __shfl_xor(pi[i], m, 64);
            pt[i] += __shfl_xor(pt[i], m, 64);
        }
    }

    const long NTD = (long)NTOT * DIM;
#pragma unroll
    for (int i = 0; i < 4; ++i){
        int r = tr + 16 * i;
        float mx = fmaxf(pi[i], pt[i]);
        float ei = __expf(pi[i] - mx), et = __expf(pt[i] - mx);
        float inv = 1.f / (ei + et);
        float wi = ei * inv, wt = et * inv;
        const float4 ie = *reinterpret_cast<const float4*>(&si[r][tc * 4]);
        const float4 te = *reinterpret_cast<const float4*>(&st[r][tc * 4]);
        float4 cm, oi, ot;
        cm.x = wi * ie.x + wt * te.x;
        cm.y = wi * ie.y + wt * te.y;
        cm.z = wi * ie.z + wt * te.z;
        cm.w = wi * ie.w + wt * te.w;
        oi.x = ie.x - cm.x; oi.y = ie.y - cm.y; oi.z = ie.z - cm.z; oi.w = ie.w - cm.w;
        ot.x = te.x - cm.x; ot.y = te.y - cm.y; ot.z = te.z - cm.z; ot.w = te.w - cm.w;
        long o = (row0 + r) * 64 + tc * 4;
        *reinterpret_cast<float4*>(out + NTD + o)     = oi;
        *reinterpret_cast<float4*>(out + 2 * NTD + o) = ot;
        *reinterpret_cast<float4*>(out + 3 * NTD + o) = cm;
    }
}

extern "C" void kernel_launch(void* const* d_in, const int* in_sizes, int n_in,
                              void* d_out, int out_size, void* d_ws, size_t ws_size,
                              hipStream_t stream){
    const float* user_emb  = (const float*)d_in[0];
    const float* item_emb  = (const float*)d_in[1];
    const float* image_emb = (const float*)d_in[2];
    const float* text_emb  = (const float*)d_in[3];
    const float* W_img = (const float*)d_in[4];
    const float* b_img = (const float*)d_in[5];
    const float* g_img = (const float*)d_in[6];
    const float* be_img= (const float*)d_in[7];
    const float* W_txt = (const float*)d_in[8];
    const float* b_txt = (const float*)d_in[9];
    const float* g_txt = (const float*)d_in[10];
    const float* be_txt= (const float*)d_in[11];
    const float* W_gi  = (const float*)d_in[12];
    const float* b_gi  = (const float*)d_in[13];
    const float* W_gt  = (const float*)d_in[14];
    const float* b_gt  = (const float*)d_in[15];
    const float* W_c1  = (const float*)d_in[16];
    const float* b_c1  = (const float*)d_in[17];
    const float* w_c2  = (const float*)d_in[18];
    const float* ui_vals = (const float*)d_in[19];
    const float* R_vals  = (const float*)d_in[20];
    const float* ii_iv   = (const float*)d_in[21];
    const float* ii_tv   = (const float*)d_in[22];
    const int* ui_rows = (const int*)d_in[23];
    const int* ui_cols = (const int*)d_in[24];
    const int* R_rows  = (const int*)d_in[25];
    const int* R_cols  = (const int*)d_in[26];
    const int* ii_ir   = (const int*)d_in[27];
    const int* ii_ic   = (const int*)d_in[28];
    const int* ii_tr   = (const int*)d_in[29];
    const int* ii_tc   = (const int*)d_in[30];

    const long ND = (long)NTOT * DIM;    // 5,120,000
    const long ID = (long)N_ITEM * DIM;  // 1,920,000
    const long UD = (long)N_USER * DIM;  // 3,200,000

    float* out = (float*)d_out;
    float* o0 = out;
    float* o1 = out + ND;
    float* o2 = out + 2 * ND;
    float* o3 = out + 3 * ND;

    // projgate outputs in o3 (dead until modal hop-2 overwrites)
    float* P_img = o3;
    float* P_txt = o3 + ID;
    // modal hop-1 outputs in o1 (o1 fully dead until pullRC): 2*ID < ND
    float* Q_img = o1;
    float* Q_txt = o1 + ID;
    // modal hop-2 outputs back into o3 (P dead after hop-1)
    float* H_img = o3;
    float* H_txt = o3 + ID;

    // binned staging (19.2 MB) lives in o0 — dead after k_scatter.
    int2* binned = (int2*)o0;

    // ---- workspace (~20 MB): combined CSR + bucket tables ----
    int2* csr   = (int2*)d_ws;                  // NNZ_ALL (19.2 MB)
    int*  off   = (int*)(csr + NNZ_ALL);        // NROWS_ALL + 1 (+pad)
    int*  bcnt  = off + NROWS_ALL + 4;          // NBUCK
    int*  bcur  = bcnt + NBUCK;                 // NBUCK (adjacent: one memset)
    int*  bbase = bcur + NBUCK;                 // NBUCK + 1

    // ---- build combined CSR ----
    hipMemsetAsync(bcnt, 0, 2 * NBUCK * sizeof(int), stream);   // bcnt + bcur
    k_bhist<<<512, 256, 0, stream>>>(ui_rows, R_rows, ii_ir, ii_tr, bcnt);
    k_bscan<<<1, 512, 0, stream>>>(bcnt, bbase, off);
    k_bin<<<NBLK_A2, 256, 0, stream>>>(
        ui_rows, ui_cols, ui_vals,  R_rows, R_cols, R_vals,
        ii_ir, ii_ic, ii_iv,        ii_tr, ii_tc, ii_tv,
        bbase, bcur, binned);
    k_scatter<<<NBUCK, 256, 0, stream>>>(bbase, binned, off, csr);

    const int* offUI = off;
    const int* offR  = off + BASE_R;
    const int* offI2 = off + BASE_II;
    const int* offT2 = off + BASE_IT;

    // ---- MEGA1: projgate first, UI hop-1 pulls behind (contiguous) ----
    k_mega1<<<NBLK_M1, 256, 0, stream>>>(
        offUI, csr, user_emb, o2,
        image_emb, W_img, b_img, g_img, be_img, W_gi, b_gi,
        text_emb,  W_txt, b_txt, g_txt, be_txt, W_gt, b_gt,
        item_emb, P_img, P_txt);

    // ---- MEGA2 (contiguous): UI hop-2 + mean (o2 -> o0), modal hop-1 (P -> Q)
    k_mega2c<<<NBLK_M2, 256, 0, stream>>>(
        offUI, csr, o2, item_emb, user_emb, o0,
        offI2, P_img, Q_img, offT2, P_txt, Q_txt);
    // o2 free from here; P dead (consumed by hop-1)

    // ---- modal hop-2: Q (o1) -> H (o3) ----
    k_pull2<<<2 * NBLK_I16, 256, 0, stream>>>(
        offI2, csr, Q_img, H_img, offT2, Q_txt, H_txt, N_ITEM, NBLK_I16);
    // Q dead; o1 free

    // ---- R-pull both modalities + item-block copies (o3 -> o1/o2 tails) ----
    k_pullRC<<<NBLK_RC, 256, 0, stream>>>(
        offR, csr, H_img, o1, H_txt, o2, o1 + UD, o2 + UD);

    // ---- fusion epilogue (reads o1/o2, writes o1/o2/o3) ----
    k_fuse<<<NTOT / 64, 256, 0, stream>>>(o1, o2, W_c1, b_c1, w_c2, out);
}